// Round 15
// baseline (1496.974 us; speedup 1.0000x reference)
//
#include <hip/hip_runtime.h>
#include <hip/hip_bf16.h>
#include <math.h>

#define EPSV 1e-8f

__device__ __forceinline__ float dsmall(float d){ return d > EPSV ? d : EPSV; }
__device__ __forceinline__ float sigf(float x){ return 1.f/(1.f+expf(-x)); }

// ---------------------------------------------------------------------------
// Transpose ctx Whh (z selects F/B): W (1024x256) -> WT (256x1024)
// ---------------------------------------------------------------------------
__global__ __launch_bounds__(1024) void k_transpose2(const float* __restrict__ WF,
                                                     const float* __restrict__ WB,
                                                     float* __restrict__ WT0,
                                                     float* __restrict__ WT1){
  const float* W = blockIdx.z ? WB : WF;
  float* WT = blockIdx.z ? WT1 : WT0;
  __shared__ float t[32][33];
  int rb = blockIdx.y*32, cb = blockIdx.x*32;
  int r = rb + threadIdx.y, c = cb + threadIdx.x;
  t[threadIdx.y][threadIdx.x] = W[(size_t)r*256 + c];
  __syncthreads();
  int rr = cb + threadIdx.y, cc = rb + threadIdx.x;
  WT[(size_t)rr*1024 + cc] = t[threadIdx.x][threadIdx.y];
}

// ---------------------------------------------------------------------------
// ctx projections: z in 0..3 (zo=z>>1: left/right; zi=z&1: F/B dir)
// ---------------------------------------------------------------------------
__global__ __launch_bounds__(256) void k_proj(
    const float* __restrict__ left, const float* __restrict__ right,
    const float* __restrict__ WihF, const float* __restrict__ WihB,
    const float* __restrict__ bF, const float* __restrict__ bB,
    float* __restrict__ PREf, float* __restrict__ PREb)
{
  const int z = blockIdx.z, zo = z >> 1, zi = z & 1;
  const float* A = zo ? right : left;
  const float* B = zi ? WihB : WihF;
  const float* bias = zi ? bB : bF;
  float* C = (zi ? PREb : PREf) + (size_t)zo*1048576;
  const int K = 300;

  __shared__ float As[16][68];
  __shared__ float Bs[16][68];
  const int mb = blockIdx.y*64, nb = blockIdx.x*64;
  const int tid = threadIdx.x;
  const int tx = tid & 15, ty = tid >> 4;

  float acc[4][4];
  #pragma unroll
  for (int i=0;i<4;i++)
    #pragma unroll
    for (int j=0;j<4;j++) acc[i][j] = 0.f;

  for (int kt = 0; kt < K; kt += 16) {
    int ka = tid & 15, ma = tid >> 4;
    #pragma unroll
    for (int q=0;q<4;q++){
      int m = ma + q*16;
      float v = 0.f, bvv = 0.f;
      if (kt+ka < K){
        v = A[(size_t)(mb+m)*300 + kt+ka];
        bvv = B[(size_t)(nb+m)*300 + kt+ka];
      }
      As[ka][m] = v; Bs[ka][m] = bvv;
    }
    __syncthreads();
    #pragma unroll
    for (int k=0;k<16;k++){
      float a[4], bv[4];
      #pragma unroll
      for (int i=0;i<4;i++) a[i] = As[k][ty*4+i];
      #pragma unroll
      for (int j=0;j<4;j++) bv[j] = Bs[k][tx*4+j];
      #pragma unroll
      for (int i=0;i<4;i++)
        #pragma unroll
        for (int j=0;j<4;j++) acc[i][j] += a[i]*bv[j];
    }
    __syncthreads();
  }
  #pragma unroll
  for (int i=0;i<4;i++){
    int m = mb + ty*4 + i;
    #pragma unroll
    for (int j=0;j<4;j++){
      int n = nb + tx*4 + j;
      C[(size_t)m*1024 + n] = acc[i][j] + bias[n];
    }
  }
}

// ---------------------------------------------------------------------------
// agg projections: z in 0..1 (F/B)
// ---------------------------------------------------------------------------
__global__ __launch_bounds__(256) void k_aggproj(
    const float* __restrict__ MV_,
    const float* __restrict__ WihF, const float* __restrict__ WihB,
    const float* __restrict__ bF, const float* __restrict__ bB,
    float* __restrict__ PREf, float* __restrict__ PREb)
{
  const int zi = blockIdx.z;
  const float* B = zi ? WihB : WihF;
  const float* bias = zi ? bB : bF;
  float* C = zi ? PREb : PREf;
  const int K = 62;

  __shared__ float As[16][68];
  __shared__ float Bs[16][68];
  const int mb = blockIdx.y*64, nb = blockIdx.x*64;
  const int tid = threadIdx.x;
  const int tx = tid & 15, ty = tid >> 4;

  float acc[4][4];
  #pragma unroll
  for (int i=0;i<4;i++)
    #pragma unroll
    for (int j=0;j<4;j++) acc[i][j] = 0.f;

  for (int kt = 0; kt < K; kt += 16) {
    int ka = tid & 15, ma = tid >> 4;
    #pragma unroll
    for (int q=0;q<4;q++){
      int m = ma + q*16;
      float v = 0.f, bvv = 0.f;
      if (kt+ka < K){
        v = MV_[(size_t)(mb+m)*62 + kt+ka];
        bvv = B[(size_t)(nb+m)*62 + kt+ka];
      }
      As[ka][m] = v; Bs[ka][m] = bvv;
    }
    __syncthreads();
    #pragma unroll
    for (int k=0;k<16;k++){
      float a[4], bv[4];
      #pragma unroll
      for (int i=0;i<4;i++) a[i] = As[k][ty*4+i];
      #pragma unroll
      for (int j=0;j<4;j++) bv[j] = Bs[k][tx*4+j];
      #pragma unroll
      for (int i=0;i<4;i++)
        #pragma unroll
        for (int j=0;j<4;j++) acc[i][j] += a[i]*bv[j];
    }
    __syncthreads();
  }
  #pragma unroll
  for (int i=0;i<4;i++){
    int m = mb + ty*4 + i;
    #pragma unroll
    for (int j=0;j<4;j++){
      int n = nb + tx*4 + j;
      C[(size_t)m*1024 + n] = acc[i][j] + bias[n];
    }
  }
}

// ---------------------------------------------------------------------------
// att cosine matrix with fused row/col sum+max partials.
// C=A@B^T / dsmall(U[m]*V[n]), z = d*4+b. Partials per 64x64 tile.
// ---------------------------------------------------------------------------
__global__ __launch_bounds__(256) void k_att(
    const float* __restrict__ HS_, const float* __restrict__ NORM_,
    float* __restrict__ ATT_,
    float* __restrict__ PRS, float* __restrict__ PRM,
    float* __restrict__ PCS, float* __restrict__ PCM)
{
  const int z = blockIdx.z;
  const int d = z >> 2, b = z & 3;
  const float* A = HS_ + d*256 + (size_t)b*131072;
  const float* B = HS_ + 524288 + d*256 + (size_t)b*131072;
  const float* Uv = NORM_ + (size_t)b*512 + d*256;
  const float* Vv = NORM_ + (size_t)(4+b)*512 + d*256;
  float* C = ATT_ + (size_t)z*65536;

  __shared__ float As[16][68];
  __shared__ float Bs[16][68];
  const int mb = blockIdx.y*64, nb = blockIdx.x*64;
  const int tid = threadIdx.x;
  const int tx = tid & 15, ty = tid >> 4;

  float acc[4][4];
  #pragma unroll
  for (int i=0;i<4;i++)
    #pragma unroll
    for (int j=0;j<4;j++) acc[i][j] = 0.f;

  for (int kt = 0; kt < 256; kt += 16) {
    int ka = tid & 15, ma = tid >> 4;
    #pragma unroll
    for (int q=0;q<4;q++){
      int m = ma + q*16;
      As[ka][m] = A[(size_t)(mb+m)*512 + kt+ka];
      Bs[ka][m] = B[(size_t)(nb+m)*512 + kt+ka];
    }
    __syncthreads();
    #pragma unroll
    for (int k=0;k<16;k++){
      float a[4], bv[4];
      #pragma unroll
      for (int i=0;i<4;i++) a[i] = As[k][ty*4+i];
      #pragma unroll
      for (int j=0;j<4;j++) bv[j] = Bs[k][tx*4+j];
      #pragma unroll
      for (int i=0;i<4;i++)
        #pragma unroll
        for (int j=0;j<4;j++) acc[i][j] += a[i]*bv[j];
    }
    __syncthreads();
  }
  float c[4][4];
  #pragma unroll
  for (int i=0;i<4;i++){
    int m = mb + ty*4 + i;
    float um = Uv[m];
    #pragma unroll
    for (int j=0;j<4;j++){
      int n = nb + tx*4 + j;
      c[i][j] = acc[i][j] / dsmall(um * Vv[n]);
      C[(size_t)m*256 + n] = c[i][j];
    }
  }
  // row partials (sum+max over this tile's 64 cols)
  float rs[4], rm[4];
  #pragma unroll
  for (int i=0;i<4;i++){
    rs[i] = c[i][0]+c[i][1]+c[i][2]+c[i][3];
    rm[i] = fmaxf(fmaxf(c[i][0], c[i][1]), fmaxf(c[i][2], c[i][3]));
    rs[i] += __shfl_xor(rs[i], 1, 64); rm[i] = fmaxf(rm[i], __shfl_xor(rm[i], 1, 64));
    rs[i] += __shfl_xor(rs[i], 2, 64); rm[i] = fmaxf(rm[i], __shfl_xor(rm[i], 2, 64));
    rs[i] += __shfl_xor(rs[i], 4, 64); rm[i] = fmaxf(rm[i], __shfl_xor(rm[i], 4, 64));
    rs[i] += __shfl_xor(rs[i], 8, 64); rm[i] = fmaxf(rm[i], __shfl_xor(rm[i], 8, 64));
  }
  if ((tid & 15) == 0){
    #pragma unroll
    for (int i=0;i<4;i++){
      PRS[((size_t)z*4 + blockIdx.x)*256 + mb + ty*4 + i] = rs[i];
      PRM[((size_t)z*4 + blockIdx.x)*256 + mb + ty*4 + i] = rm[i];
    }
  }
  // col partials via LDS
  __syncthreads();
  float* csum = &As[0][0];
  float* cmax = &Bs[0][0];
  #pragma unroll
  for (int j=0;j<4;j++){
    csum[ty*64 + tx*4 + j] = c[0][j]+c[1][j]+c[2][j]+c[3][j];
    cmax[ty*64 + tx*4 + j] = fmaxf(fmaxf(c[0][j], c[1][j]), fmaxf(c[2][j], c[3][j]));
  }
  __syncthreads();
  if (tid < 64){
    float s = 0.f, m = -INFINITY;
    #pragma unroll
    for (int r=0;r<16;r++){ s += csum[r*64 + tid]; m = fmaxf(m, cmax[r*64 + tid]); }
    PCS[((size_t)z*4 + blockIdx.y)*256 + nb + tid] = s;
    PCM[((size_t)z*4 + blockIdx.y)*256 + nb + tid] = m;
  }
}

__global__ void k_attcomb(const float* __restrict__ PRS, const float* __restrict__ PRM,
                          const float* __restrict__ PCS, const float* __restrict__ PCM,
                          float* __restrict__ RS_, float* __restrict__ RMAX_,
                          float* __restrict__ CS_, float* __restrict__ CMAX_){
  int z = blockIdx.x, j = threadIdx.x;
  float rs=0.f, rm=-INFINITY, cs=0.f, cm=-INFINITY;
  #pragma unroll
  for (int p=0;p<4;p++){
    size_t o = ((size_t)z*4 + p)*256 + j;
    rs += PRS[o]; rm = fmaxf(rm, PRM[o]);
    cs += PCS[o]; cm = fmaxf(cm, PCM[o]);
  }
  RS_[z*256 + j] = rs;  RMAX_[z*256 + j] = rm;
  CS_[z*256 + j] = cs;  CMAX_[z*256 + j] = cm;
}

// ---------------------------------------------------------------------------
// Fused attentive stats
// ---------------------------------------------------------------------------
__global__ __launch_bounds__(256) void k_attstat(
    const float* __restrict__ ATT_, const float* __restrict__ HS_,
    const float* __restrict__ RS_, const float* __restrict__ CS_,
    float* __restrict__ MEANH_, float* __restrict__ XH_,
    float* __restrict__ MEANP_, float* __restrict__ XP_)
{
  const int z16 = blockIdx.z;
  const int var = z16 >> 3;
  const int z = z16 & 7;
  const int d = z >> 2, b = z & 3;
  const float* A = ATT_ + (size_t)z*65536;
  const float* B = (var ? HS_ : HS_ + 524288) + d*256 + (size_t)b*131072;
  const float* U = (var ? CS_ : RS_) + z*256;
  float* C1 = (var ? MEANP_ : MEANH_) + (size_t)z*65536;
  float* C2 = (var ? XP_    : XH_   ) + (size_t)z*65536;

  __shared__ float As[16][68];
  __shared__ float Bs[16][68];
  const int mb = blockIdx.y*64, nb = blockIdx.x*64;
  const int tid = threadIdx.x;
  const int tx = tid & 15, ty = tid >> 4;

  float asum[4][4], amax[4][4];
  #pragma unroll
  for (int i=0;i<4;i++)
    #pragma unroll
    for (int j=0;j<4;j++){ asum[i][j]=0.f; amax[i][j]=-INFINITY; }

  for (int kt = 0; kt < 256; kt += 16) {
    if (var == 0) {
      int ka = tid & 15, ma = tid >> 4;
      #pragma unroll
      for (int q=0;q<4;q++)
        As[ka][ma+q*16] = A[(size_t)(mb+ma+q*16)*256 + kt+ka];
    } else {
      int ma = tid & 63, ka = tid >> 6;
      #pragma unroll
      for (int q=0;q<4;q++)
        As[ka+q*4][ma] = A[(size_t)(kt+ka+q*4)*256 + mb+ma];
    }
    {
      int nbi = tid & 63, kb = tid >> 6;
      #pragma unroll
      for (int q=0;q<4;q++)
        Bs[kb+q*4][nbi] = B[(size_t)(kt+kb+q*4)*512 + nb+nbi];
    }
    __syncthreads();
    #pragma unroll
    for (int k=0;k<16;k++){
      float a[4], bv[4];
      #pragma unroll
      for (int i=0;i<4;i++) a[i] = As[k][ty*4+i];
      #pragma unroll
      for (int j=0;j<4;j++) bv[j] = Bs[k][tx*4+j];
      #pragma unroll
      for (int i=0;i<4;i++)
        #pragma unroll
        for (int j=0;j<4;j++){
          float p = a[i]*bv[j];
          asum[i][j] += p;
          amax[i][j] = fmaxf(amax[i][j], p);
        }
    }
    __syncthreads();
  }
  #pragma unroll
  for (int i=0;i<4;i++){
    int m = mb + ty*4 + i;
    float ud = dsmall(U[m]);
    #pragma unroll
    for (int j=0;j<4;j++){
      int n = nb + tx*4 + j;
      C1[(size_t)m*256 + n] = asum[i][j] / ud;
      C2[(size_t)m*256 + n] = amax[i][j];
    }
  }
}

// ---------------------------------------------------------------------------
// Pairwise mp-match, fw+bw in one launch: z in 0..79 (dir = z>=40)
// ---------------------------------------------------------------------------
__global__ __launch_bounds__(256) void k_pmm2(
    const float* __restrict__ HS_,
    const float* __restrict__ w3, const float* __restrict__ w4,
    const float* __restrict__ WN1_, const float* __restrict__ WN2_,
    float* __restrict__ PARTR, float* __restrict__ PARTC)
{
  const int z = blockIdx.z;
  const int dir = z >= 40;
  const int zz = z - dir*40;
  const int bq = zz / 10, l = zz % 10;
  const float* A = HS_ + dir*256 + (size_t)bq*131072;
  const float* B = HS_ + 524288 + dir*256 + (size_t)bq*131072;
  const float* Wv = (dir ? w4 : w3) + l*256;
  const float* U = WN1_ + dir*10240 + bq*2560 + l*256;
  const float* V = WN2_ + dir*10240 + bq*2560 + l*256;

  __shared__ float As[16][68];
  __shared__ float Bs[16][68];
  const int mb = blockIdx.y*64, nb = blockIdx.x*64;
  const int tid = threadIdx.x;
  const int tx = tid & 15, ty = tid >> 4;

  float acc[4][4];
  #pragma unroll
  for (int i=0;i<4;i++)
    #pragma unroll
    for (int j=0;j<4;j++) acc[i][j] = 0.f;

  for (int kt = 0; kt < 256; kt += 16) {
    int ka = tid & 15, ma = tid >> 4;
    float w = Wv[kt+ka]; float w2 = w*w;
    #pragma unroll
    for (int q=0;q<4;q++){
      As[ka][ma+q*16] = A[(size_t)(mb+ma+q*16)*512 + kt+ka] * w2;
      Bs[ka][ma+q*16] = B[(size_t)(nb+ma+q*16)*512 + kt+ka];
    }
    __syncthreads();
    #pragma unroll
    for (int k=0;k<16;k++){
      float a[4], bv[4];
      #pragma unroll
      for (int i=0;i<4;i++) a[i] = As[k][ty*4+i];
      #pragma unroll
      for (int j=0;j<4;j++) bv[j] = Bs[k][tx*4+j];
      #pragma unroll
      for (int i=0;i<4;i++)
        #pragma unroll
        for (int j=0;j<4;j++) acc[i][j] += a[i]*bv[j];
    }
    __syncthreads();
  }
  float um[4], vn[4];
  #pragma unroll
  for (int i=0;i<4;i++) um[i] = U[mb + ty*4 + i];
  #pragma unroll
  for (int j=0;j<4;j++) vn[j] = V[nb + tx*4 + j];
  float c[4][4];
  #pragma unroll
  for (int i=0;i<4;i++)
    #pragma unroll
    for (int j=0;j<4;j++) c[i][j] = acc[i][j] / dsmall(um[i]*vn[j]);

  float rm[4];
  #pragma unroll
  for (int i=0;i<4;i++){
    rm[i] = fmaxf(fmaxf(c[i][0], c[i][1]), fmaxf(c[i][2], c[i][3]));
    rm[i] = fmaxf(rm[i], __shfl_xor(rm[i], 1, 64));
    rm[i] = fmaxf(rm[i], __shfl_xor(rm[i], 2, 64));
    rm[i] = fmaxf(rm[i], __shfl_xor(rm[i], 4, 64));
    rm[i] = fmaxf(rm[i], __shfl_xor(rm[i], 8, 64));
  }
  if ((tid & 15) == 0){
    #pragma unroll
    for (int i=0;i<4;i++)
      PARTR[((size_t)z*4 + blockIdx.x)*256 + mb + ty*4 + i] = rm[i];
  }
  __syncthreads();
  float* colp = &As[0][0];
  #pragma unroll
  for (int j=0;j<4;j++)
    colp[ty*64 + tx*4 + j] = fmaxf(fmaxf(c[0][j], c[1][j]), fmaxf(c[2][j], c[3][j]));
  __syncthreads();
  if (tid < 64){
    float m = colp[tid];
    #pragma unroll
    for (int r=1;r<16;r++) m = fmaxf(m, colp[r*64 + tid]);
    PARTC[((size_t)z*4 + blockIdx.y)*256 + nb + tid] = m;
  }
}

__global__ void k_pcomb(const float* __restrict__ PARTR, const float* __restrict__ PARTC,
                        float* __restrict__ MMRo, float* __restrict__ MMCo){
  int z = blockIdx.x, i = threadIdx.x;
  size_t b0 = (size_t)z*4*256 + i;
  float r = fmaxf(fmaxf(PARTR[b0], PARTR[b0+256]), fmaxf(PARTR[b0+512], PARTR[b0+768]));
  float c = fmaxf(fmaxf(PARTC[b0], PARTC[b0+256]), fmaxf(PARTC[b0+512], PARTC[b0+768]));
  MMRo[(size_t)z*256 + i] = r;
  MMCo[(size_t)z*256 + i] = c;
}

// ---------------------------------------------------------------------------
// LSTM scan v13: 16 teams (8/dir) x 8 WGs, 1 seq per team, EARLY FLAG:
// with 1 seq/team all Hb stores come from wave 0 (tid<32), so wave 0 drains
// its own vmcnt and posts the flag BEFORE B2 -- removing the all-wave
// barrier-arrival wait from the producer->consumer chain. Reuse-distance-2
// safety unchanged (flag still certifies drained data; consumption ordering
// via B1 as before). bx>=128: aux work during ctx scan.
// ---------------------------------------------------------------------------
__global__ __launch_bounds__(256, 1) void k_scanaux(
    const float* __restrict__ PREf, const float* __restrict__ PREb,
    const float* __restrict__ WTf, const float* __restrict__ WTb,
    float* __restrict__ Hbuf, int* __restrict__ flg,
    float* __restrict__ HSo, float* __restrict__ HTo,
    int do_aux,
    const float* __restrict__ fc1W, float* __restrict__ W1T,
    const float* __restrict__ aWhhF, float* __restrict__ WTaggF,
    const float* __restrict__ aWhhB, float* __restrict__ WTaggB,
    const float* __restrict__ left, const float* __restrict__ right,
    float* __restrict__ XM)
{
  __shared__ float Wl[256][128];     // 128 KB (aux reuses as 32x33 tile)
  __shared__ float hl[256];          // 1 KB
  __shared__ float red[4][4][40];    // 2.5 KB red[kp][cc][gq]

  const int bx = blockIdx.x;
  const int tid = threadIdx.x;

  if (bx >= 128) {
    if (!do_aux) return;
    float (*tl)[33] = (float(*)[33])Wl;
    const int aux = bx - 128;         // 0..63
    for (int u = aux; u < 816 + 512 + 8; u += 64) {
      if (u < 816) {                // fc1W (512x1626) -> W1T (1626x512)
        int tI = u % 16, tJ = u / 16;
        int r0 = tI*32, c0 = tJ*32;
        for (int e = tid; e < 1024; e += 256) {
          int rr = e >> 5, cc = e & 31;
          int c = c0 + cc;
          tl[rr][cc] = (c < 1626) ? fc1W[(size_t)(r0+rr)*1626 + c] : 0.f;
        }
        __syncthreads();
        for (int e = tid; e < 1024; e += 256) {
          int cc = e >> 5, rr = e & 31;
          int c = c0 + cc;
          if (c < 1626) W1T[(size_t)c*512 + r0 + rr] = tl[rr][cc];
        }
        __syncthreads();
      } else if (u < 1328) {        // aWhh (1024x256) -> WTagg (256x1024)
        int u2 = u - 816;
        const float* S = (u2 >= 256) ? aWhhB : aWhhF;
        float* D = (u2 >= 256) ? WTaggB : WTaggF;
        int tile = u2 & 255;
        int r0 = (tile >> 3)*32, c0 = (tile & 7)*32;
        for (int e = tid; e < 1024; e += 256) {
          int rr = e >> 5, cc = e & 31;
          tl[rr][cc] = S[(size_t)(r0+rr)*256 + c0 + cc];
        }
        __syncthreads();
        for (int e = tid; e < 1024; e += 256) {
          int cc = e >> 5, rr = e & 31;
          D[(size_t)(c0+cc)*1024 + r0 + rr] = tl[rr][cc];
        }
        __syncthreads();
      } else {                      // means
        int m = u - 1328;
        int b = m & 3, sideR = m >> 2;
        const float* src = sideR ? right : left;
        for (int ch = tid; ch < 300; ch += 256) {
          float s = 0.f;
          for (int t = 0; t < 256; t++) s += src[((size_t)(b*256+t))*300 + ch];
          XM[b*600 + sideR*300 + ch] = s * (1.f/256.f);
        }
      }
    }
    return;
  }

  // ----------------- scan path -----------------
  const int team = bx & 15;
  const int d  = team >> 3;
  const int sq = team & 7;
  const int wg = bx >> 4;
  const float* PRE = d ? PREb : PREf;
  const float* WT  = d ? WTb  : WTf;
  float* Hb = Hbuf + (size_t)team*512;
  int* fl = flg + team*256;

  const int kc = tid >> 5;   // k-chunk 0..7
  const int gq = tid & 31;
  const int aj = tid & 31;   // activation col (tid<32)

  for (int e = tid; e < 256*128; e += 256) {
    int k = e >> 7, c = e & 127;
    Wl[k][c] = WT[(size_t)k*1024 + (c>>5)*256 + wg*32 + (c&31)];
  }
  hl[tid] = 0.f;
  float cst = 0.f;
  __syncthreads();

  for (int tt = 0; tt < 256; ++tt) {
    const int t = d ? 255 - tt : tt;
    const int wp = tt & 1;
    const int sp = (tt + 1) & 1;

    // prefetch PRE (tid<32)
    float pre0=0.f, pre1=0.f, pre2=0.f, pre3=0.f;
    if (tid < 32) {
      const size_t pbase = ((size_t)(sq*256 + t))*1024 + wg*32 + aj;
      pre0 = PRE[pbase];       pre1 = PRE[pbase + 256];
      pre2 = PRE[pbase + 512]; pre3 = PRE[pbase + 768];
    }

    // per-half-wave fetch of remote chunk kc (32 floats = 128B)
    if (tt > 0 && kc != wg) {
      const int* flp = &fl[kc*32];
      while (__hip_atomic_load(flp, __ATOMIC_RELAXED, __HIP_MEMORY_SCOPE_AGENT) < tt)
        __builtin_amdgcn_s_sleep(1);
      float v = __hip_atomic_load(&Hb[sp*256 + kc*32 + gq],
                                  __ATOMIC_RELAXED, __HIP_MEMORY_SCOPE_AGENT);
      hl[kc*32 + gq] = v;
    }

    // gate matmul: acc[cc] over 32 k of chunk kc
    float acc[4] = {0.f, 0.f, 0.f, 0.f};
    #pragma unroll 8
    for (int kk = 0; kk < 32; ++kk) {
      const int k = kc*32 + kk;
      float4 w = *(const float4*)&Wl[k][gq*4];
      float h = hl[k];
      acc[0] += h*w.x; acc[1] += h*w.y; acc[2] += h*w.z; acc[3] += h*w.w;
    }
    #pragma unroll
    for (int c2=0;c2<4;c2++)
      acc[c2] += __shfl_xor(acc[c2], 32, 64);
    if ((tid & 32) == 0) {
      const int kp = kc >> 1;
      #pragma unroll
      for (int c2=0;c2<4;c2++)
        red[kp][c2][gq] = acc[c2];
    }
    __syncthreads();   // B1

    float hreg = 0.f;
    if (tid < 32) {
      float g[4];
      #pragma unroll
      for (int gt=0; gt<4; ++gt) {
        const int c = gt*32 + aj;
        const int gqq = c >> 2, cc = c & 3;
        g[gt] = red[0][cc][gqq] + red[1][cc][gqq] + red[2][cc][gqq] + red[3][cc][gqq];
      }
      g[0] += pre0; g[1] += pre1; g[2] += pre2; g[3] += pre3;
      const float ig = sigf(g[0]), fg = sigf(g[1]), gg = tanhf(g[2]), og = sigf(g[3]);
      cst = fg*cst + ig*gg;
      hreg = og*tanhf(cst);
      hl[wg*32 + aj] = hreg;
      __hip_atomic_store(&Hb[wp*256 + wg*32 + aj], hreg,
                         __ATOMIC_RELAXED, __HIP_MEMORY_SCOPE_AGENT);
    }
    // EARLY FLAG: wave 0 (contains all Hb writers) drains + posts before B2
    if (tid < 64) {
      asm volatile("s_waitcnt vmcnt(0)" ::: "memory");
      if (tid == 0)
        __hip_atomic_store(&fl[wg*32], tt+1, __ATOMIC_RELAXED, __HIP_MEMORY_SCOPE_AGENT);
    }
    // off-critical-path outputs
    if (tid < 32) {
      if (HSo) HSo[((size_t)(sq*256 + t))*512 + d*256 + wg*32 + aj] = hreg;
      if (HTo && tt == 255) HTo[((size_t)(sq*2 + d))*256 + wg*32 + aj] = hreg;
    }
    __syncthreads();   // B2: hl own-chunk visibility for next step
  }
}

// ---------------------------------------------------------------------------
// Norms: bx<1024 -> row L2 norms of HS; else weighted norms
// ---------------------------------------------------------------------------
__global__ __launch_bounds__(256) void k_norms(const float* __restrict__ HS_,
                                               const float* __restrict__ w3, const float* __restrict__ w4,
                                               float* __restrict__ NORM_,
                                               float* __restrict__ WN1_, float* __restrict__ WN2_){
  const int bx = blockIdx.x;
  int lane = threadIdx.x & 63;
  if (bx < 1024) {
    int r = bx*4 + (threadIdx.x >> 6);
    int seq = r >> 9, d = (r >> 8) & 1, i = r & 255;
    const float* row = HS_ + ((size_t)(seq*256 + i))*512 + d*256;
    float s = 0.f;
    #pragma unroll
    for (int q=0;q<4;q++){ float v = row[lane + 64*q]; s += v*v; }
    for (int off=32; off; off>>=1) s += __shfl_xor(s, off, 64);
    if (lane == 0) NORM_[r] = sqrtf(s);
  } else {
    int rid = (bx-1024)*4 + (threadIdx.x >> 6);
    int side = rid / 20480; int rem = rid % 20480;
    int d = rem / 10240; int rem2 = rem % 10240;
    int b = rem2 / 2560; int l = (rem2 / 256) % 10; int i = rem2 & 255;
    int seq = side ? 4+b : b;
    const float* row = HS_ + ((size_t)(seq*256 + i))*512 + d*256;
    const float* w = (d ? w4 : w3) + l*256;
    float s = 0.f;
    #pragma unroll
    for (int q=0;q<4;q++){ float wv = w[lane+64*q]; float v = row[lane+64*q]; s += wv*wv*v*v; }
    for (int off=32; off; off>>=1) s += __shfl_xor(s, off, 64);
    if (lane == 0) (side ? WN2_ : WN1_)[rem] = sqrtf(s);
  }
}

// ---------------------------------------------------------------------------
// Assemble mv rows (62 channels)
// ---------------------------------------------------------------------------
__global__ __launch_bounds__(256) void k_mv(
    const float* __restrict__ HS_, const float* __restrict__ MEANH_, const float* __restrict__ MEANP_,
    const float* __restrict__ XH_, const float* __restrict__ XP_,
    const float* __restrict__ RS_, const float* __restrict__ RMAX_,
    const float* __restrict__ CS_, const float* __restrict__ CMAX_,
    const float* __restrict__ MMR_, const float* __restrict__ MMC_,
    const float* __restrict__ w5, const float* __restrict__ w6,
    const float* __restrict__ w7, const float* __restrict__ w8,
    float* __restrict__ MV_)
{
  const int blk = blockIdx.x;
  const int side = blk >> 10, b = (blk >> 8) & 3, i = blk & 255;
  const int wv = threadIdx.x >> 6, lane = threadIdx.x & 63;
  float* mvrow = MV_ + (size_t)blk*62;

  if (threadIdx.x == 0){
    const float* rmax = side ? CMAX_ : RMAX_;
    const float* rsum = side ? CS_   : RS_;
    mvrow[0] = rmax[b*256 + i];
    mvrow[1] = rsum[b*256 + i] * (1.f/256.f);
  }
  if (threadIdx.x < 20){
    int dd = threadIdx.x / 10, l = threadIdx.x % 10;
    const float* mm = side ? MMC_ : MMR_;
    mvrow[2 + dd*10 + l] = mm[dd*10240 + (b*10 + l)*256 + i];
  }
  const int d = wv & 1;
  const int seq = side ? 4+b : b;
  const float* arow = HS_ + ((size_t)(seq*256 + i))*512 + d*256;
  const float* Mside = side ? MEANP_ : MEANH_;
  const float* Xside = side ? XP_ : XH_;
  const float* brow = (wv < 2 ? Mside : Xside) + (size_t)d*262144 + (size_t)b*65536 + (size_t)i*256;
  const float* wp = (wv==0) ? w5 : (wv==1) ? w6 : (wv==2) ? w7 : w8;

  float av[4], bv[4];
  #pragma unroll
  for (int q=0;q<4;q++){ av[q] = arow[lane+64*q]; bv[q] = brow[lane+64*q]; }
  for (int l=0;l<10;l++){
    const float* wrow = wp + l*256;
    float s1=0.f, s2=0.f, s3=0.f;
    #pragma unroll
    for (int q=0;q<4;q++){
      float w = wrow[lane+64*q]; float w2v = w*w;
      s1 += w2v*av[q]*bv[q]; s2 += w2v*av[q]*av[q]; s3 += w2v*bv[q]*bv[q];
    }
    for (int off=32; off; off>>=1){
      s1 += __shfl_xor(s1,off,64); s2 += __shfl_xor(s2,off,64); s3 += __shfl_xor(s3,off,64);
    }
    if (lane == 0) mvrow[22 + wv*10 + l] = s1 / fmaxf(sqrtf(s2)*sqrtf(s3), EPSV);
  }
}

// ---------------------------------------------------------------------------
// Fused head: fc1 (tanh) + fc2
// ---------------------------------------------------------------------------
__global__ __launch_bounds__(512) void k_fc12(const float* __restrict__ HT_,
                                              const float* __restrict__ XM,
                                              const float* __restrict__ W1T,
                                              const float* __restrict__ b1,
                                              const float* __restrict__ W2,
                                              const float* __restrict__ b2,
                                              float* __restrict__ out){
  __shared__ float x[1626];
  __shared__ float xs2[512];
  int b = blockIdx.x, t = threadIdx.x;
  if (t < 256){
    x[t]       = HT_[(b*2+0)*256 + t];
    x[256+t]   = HT_[(b*2+1)*256 + t];
    x[512+t]   = HT_[((4+b)*2+0)*256 + t];
    x[768+t]   = HT_[((4+b)*2+1)*256 + t];
  }
  if (t == 0){ x[1024] = 0.5f; x[1025] = 0.5f; }
  if (t < 300){ x[1026+t] = XM[b*600 + t]; x[1326+t] = XM[b*600 + 300 + t]; }
  __syncthreads();
  float acc = b1[t];
  for (int k=0;k<1626;k++) acc += x[k]*W1T[(size_t)k*512 + t];
  xs2[t] = tanhf(acc);
  __syncthreads();
  if (t < 22){
    float o = b2[t];
    const float* wr = W2 + (size_t)t*512;
    for (int k=0;k<512;k++) o += xs2[k]*wr[k];
    out[b*22 + t] = o;
  }
}

// ---------------------------------------------------------------------------
extern "C" void kernel_launch(void* const* d_in, const int* in_sizes, int n_in,
                              void* d_out, int out_size, void* d_ws, size_t ws_size,
                              hipStream_t stream) {
  const float* left  = (const float*)d_in[0];
  const float* right = (const float*)d_in[1];
  const float* cWihF = (const float*)d_in[2];
  const float* cWhhF = (const float*)d_in[3];
  const float* cbF   = (const float*)d_in[4];
  const float* cWihB = (const float*)d_in[5];
  const float* cWhhB = (const float*)d_in[6];
  const float* cbB   = (const float*)d_in[7];
  const float* aWihF = (const float*)d_in[8];
  const float* aWhhF = (const float*)d_in[9];
  const float* abF   = (const float*)d_in[10];
  const float* aWihB = (const float*)d_in[11];
  const float* aWhhB = (const float*)d_in[12];
  const float* abB   = (const float*)d_in[13];
  const float* w3 = (const float*)d_in[14];
  const float* w4 = (const float*)d_in[15];
  const float* w5 = (const float*)d_in[16];
  const float* w6 = (const float*)d_in[17];
  const float* w7 = (const float*)d_in[18];
  const float* w8 = (const float*)d_in[19];
  const float* fc1W = (const float*)d_in[20];
  const float* fc1b = (const float*)d_in[21];
  const float* fc2W = (const float*)d_in[22];
  const float* fc2b = (const float*)d_in[23];
  float* out = (float*)d_out;
  float* ws = (float*)d_ws;

  // workspace layout (floats)
  float* WT    = ws;                 // 4 * 262144
  float* PREf  = ws + 1048576;       // 2097152
  float* PREb  = ws + 3145728;       // 2097152
  float* HS    = ws + 5242880;       // 1048576
  float* NORM  = ws + 6291456;       // 4096
  float* ATT   = ws + 6295552;       // 524288
  float* RS    = ws + 6819840;       // 2048
  float* RMAX  = ws + 6821888;       // 2048
  float* CS    = ws + 6823936;       // 2048
  float* CMAX  = ws + 6825984;       // 2048
  float* MEANH = ws + 6828032;       // 524288
  float* MEANP = ws + 7352320;       // 524288
  float* XH    = ws + 7876608;       // 524288
  float* XP    = ws + 8400896;       // 524288
  float* WN1   = ws + 8925184;       // 20480
  float* WN2   = ws + 8945664;       // 20480
  float* MM    = ws + 8966144;       // 2621440 scratch
  float* MMR   = ws + 11587584;      // 20480
  float* MMC   = ws + 11608064;      // 20480
  float* MV    = ws + 11628544;      // 126976
  float* HT    = ws + 11755520;      // 4096
  float* XM    = ws + 11759616;      // 2400
  float* W1T   = ws + 11764064;      // 832512

  // MM overlays (time-multiplexed)
  float* HXB  = MM;                   // scans: 8192 floats (16 teams x 512)
  int*   FLG  = (int*)(MM + 8192);    // scans: 4096 ints
  float* PRS  = MM;                   // att partials: 4 x 8192
  float* PRM  = MM + 8192;
  float* PCS  = MM + 16384;
  float* PCM  = MM + 24576;
  float* PARTR= MM;                   // pairwise: 81920
  float* PARTC= MM + 81920;           // 81920

  // 1. ctx Whh transposes
  k_transpose2<<<dim3(8,32,2), dim3(32,32), 0, stream>>>(cWhhF, cWhhB, WT, WT + 262144);

  // 2. ctx projections
  k_proj<<<dim3(16,16,4),256,0,stream>>>(left, right, cWihF, cWihB, cbF, cbB, PREf, PREb);

  // 3. ctx scan (8 teams/dir, 1 seq/team, early flag) + hidden aux work
  hipMemsetAsync(FLG, 0, 4096*sizeof(int), stream);
  k_scanaux<<<192,256,0,stream>>>(PREf, PREb, WT, WT+262144, HXB, FLG, HS, nullptr,
                                  1, fc1W, W1T, aWhhF, WT+524288, aWhhB, WT+786432,
                                  left, right, XM);

  // 4. norms
  k_norms<<<11264,256,0,stream>>>(HS, w3, w4, NORM, WN1, WN2);

  // 5. att cosine matrix with fused reduction partials + combine
  k_att<<<dim3(4,4,8),256,0,stream>>>(HS, NORM, ATT, PRS, PRM, PCS, PCM);
  k_attcomb<<<8,256,0,stream>>>(PRS, PRM, PCS, PCM, RS, RMAX, CS, CMAX);

  // 6. attentive means and maxes
  k_attstat<<<dim3(4,4,16),256,0,stream>>>(ATT, HS, RS, CS, MEANH, XH, MEANP, XP);

  // 7. pairwise mp-match + combine
  k_pmm2<<<dim3(4,4,80),256,0,stream>>>(HS, w3, w4, WN1, WN2, PARTR, PARTC);
  k_pcomb<<<80,256,0,stream>>>(PARTR, PARTC, MMR, MMC);

  // 8. assemble mv
  k_mv<<<2048,256,0,stream>>>(HS, MEANH, MEANP, XH, XP, RS, RMAX, CS, CMAX,
                              MMR, MMC, w5, w6, w7, w8, MV);

  // 9. agg projections
  k_aggproj<<<dim3(16,32,2),256,0,stream>>>(MV, aWihF, aWihB, abF, abB, PREf, PREb);

  // 10. agg scan (no aux)
  hipMemsetAsync(FLG, 0, 4096*sizeof(int), stream);
  k_scanaux<<<192,256,0,stream>>>(PREf, PREb, WT+524288, WT+786432, HXB, FLG, nullptr, HT,
                                  0, fc1W, W1T, aWhhF, WT+524288, aWhhB, WT+786432,
                                  left, right, XM);

  // 11. fused head
  k_fc12<<<4,512,0,stream>>>(HT, XM, W1T, fc1b, fc2W, fc2b, out);
}

// Round 16
// 1360.901 us; speedup vs baseline: 1.1000x; 1.1000x over previous
//
#include <hip/hip_runtime.h>
#include <hip/hip_bf16.h>
#include <math.h>

#define EPSV 1e-8f

__device__ __forceinline__ float dsmall(float d){ return d > EPSV ? d : EPSV; }
__device__ __forceinline__ float sigf(float x){ return 1.f/(1.f+expf(-x)); }

// ---------------------------------------------------------------------------
// Transpose ctx Whh (z selects F/B): W (1024x256) -> WT (256x1024)
// ---------------------------------------------------------------------------
__global__ __launch_bounds__(1024) void k_transpose2(const float* __restrict__ WF,
                                                     const float* __restrict__ WB,
                                                     float* __restrict__ WT0,
                                                     float* __restrict__ WT1){
  const float* W = blockIdx.z ? WB : WF;
  float* WT = blockIdx.z ? WT1 : WT0;
  __shared__ float t[32][33];
  int rb = blockIdx.y*32, cb = blockIdx.x*32;
  int r = rb + threadIdx.y, c = cb + threadIdx.x;
  t[threadIdx.y][threadIdx.x] = W[(size_t)r*256 + c];
  __syncthreads();
  int rr = cb + threadIdx.y, cc = rb + threadIdx.x;
  WT[(size_t)rr*1024 + cc] = t[threadIdx.x][threadIdx.y];
}

// ---------------------------------------------------------------------------
// ctx projections: z in 0..3 (zo=z>>1: left/right; zi=z&1: F/B dir)
// ---------------------------------------------------------------------------
__global__ __launch_bounds__(256) void k_proj(
    const float* __restrict__ left, const float* __restrict__ right,
    const float* __restrict__ WihF, const float* __restrict__ WihB,
    const float* __restrict__ bF, const float* __restrict__ bB,
    float* __restrict__ PREf, float* __restrict__ PREb)
{
  const int z = blockIdx.z, zo = z >> 1, zi = z & 1;
  const float* A = zo ? right : left;
  const float* B = zi ? WihB : WihF;
  const float* bias = zi ? bB : bF;
  float* C = (zi ? PREb : PREf) + (size_t)zo*1048576;
  const int K = 300;

  __shared__ float As[16][68];
  __shared__ float Bs[16][68];
  const int mb = blockIdx.y*64, nb = blockIdx.x*64;
  const int tid = threadIdx.x;
  const int tx = tid & 15, ty = tid >> 4;

  float acc[4][4];
  #pragma unroll
  for (int i=0;i<4;i++)
    #pragma unroll
    for (int j=0;j<4;j++) acc[i][j] = 0.f;

  for (int kt = 0; kt < K; kt += 16) {
    int ka = tid & 15, ma = tid >> 4;
    #pragma unroll
    for (int q=0;q<4;q++){
      int m = ma + q*16;
      float v = 0.f, bvv = 0.f;
      if (kt+ka < K){
        v = A[(size_t)(mb+m)*300 + kt+ka];
        bvv = B[(size_t)(nb+m)*300 + kt+ka];
      }
      As[ka][m] = v; Bs[ka][m] = bvv;
    }
    __syncthreads();
    #pragma unroll
    for (int k=0;k<16;k++){
      float a[4], bv[4];
      #pragma unroll
      for (int i=0;i<4;i++) a[i] = As[k][ty*4+i];
      #pragma unroll
      for (int j=0;j<4;j++) bv[j] = Bs[k][tx*4+j];
      #pragma unroll
      for (int i=0;i<4;i++)
        #pragma unroll
        for (int j=0;j<4;j++) acc[i][j] += a[i]*bv[j];
    }
    __syncthreads();
  }
  #pragma unroll
  for (int i=0;i<4;i++){
    int m = mb + ty*4 + i;
    #pragma unroll
    for (int j=0;j<4;j++){
      int n = nb + tx*4 + j;
      C[(size_t)m*1024 + n] = acc[i][j] + bias[n];
    }
  }
}

// ---------------------------------------------------------------------------
// agg projections: z in 0..1 (F/B)
// ---------------------------------------------------------------------------
__global__ __launch_bounds__(256) void k_aggproj(
    const float* __restrict__ MV_,
    const float* __restrict__ WihF, const float* __restrict__ WihB,
    const float* __restrict__ bF, const float* __restrict__ bB,
    float* __restrict__ PREf, float* __restrict__ PREb)
{
  const int zi = blockIdx.z;
  const float* B = zi ? WihB : WihF;
  const float* bias = zi ? bB : bF;
  float* C = zi ? PREb : PREf;
  const int K = 62;

  __shared__ float As[16][68];
  __shared__ float Bs[16][68];
  const int mb = blockIdx.y*64, nb = blockIdx.x*64;
  const int tid = threadIdx.x;
  const int tx = tid & 15, ty = tid >> 4;

  float acc[4][4];
  #pragma unroll
  for (int i=0;i<4;i++)
    #pragma unroll
    for (int j=0;j<4;j++) acc[i][j] = 0.f;

  for (int kt = 0; kt < K; kt += 16) {
    int ka = tid & 15, ma = tid >> 4;
    #pragma unroll
    for (int q=0;q<4;q++){
      int m = ma + q*16;
      float v = 0.f, bvv = 0.f;
      if (kt+ka < K){
        v = MV_[(size_t)(mb+m)*62 + kt+ka];
        bvv = B[(size_t)(nb+m)*62 + kt+ka];
      }
      As[ka][m] = v; Bs[ka][m] = bvv;
    }
    __syncthreads();
    #pragma unroll
    for (int k=0;k<16;k++){
      float a[4], bv[4];
      #pragma unroll
      for (int i=0;i<4;i++) a[i] = As[k][ty*4+i];
      #pragma unroll
      for (int j=0;j<4;j++) bv[j] = Bs[k][tx*4+j];
      #pragma unroll
      for (int i=0;i<4;i++)
        #pragma unroll
        for (int j=0;j<4;j++) acc[i][j] += a[i]*bv[j];
    }
    __syncthreads();
  }
  #pragma unroll
  for (int i=0;i<4;i++){
    int m = mb + ty*4 + i;
    #pragma unroll
    for (int j=0;j<4;j++){
      int n = nb + tx*4 + j;
      C[(size_t)m*1024 + n] = acc[i][j] + bias[n];
    }
  }
}

// ---------------------------------------------------------------------------
// att cosine matrix with fused row/col sum+max partials.
// ---------------------------------------------------------------------------
__global__ __launch_bounds__(256) void k_att(
    const float* __restrict__ HS_, const float* __restrict__ NORM_,
    float* __restrict__ ATT_,
    float* __restrict__ PRS, float* __restrict__ PRM,
    float* __restrict__ PCS, float* __restrict__ PCM)
{
  const int z = blockIdx.z;
  const int d = z >> 2, b = z & 3;
  const float* A = HS_ + d*256 + (size_t)b*131072;
  const float* B = HS_ + 524288 + d*256 + (size_t)b*131072;
  const float* Uv = NORM_ + (size_t)b*512 + d*256;
  const float* Vv = NORM_ + (size_t)(4+b)*512 + d*256;
  float* C = ATT_ + (size_t)z*65536;

  __shared__ float As[16][68];
  __shared__ float Bs[16][68];
  const int mb = blockIdx.y*64, nb = blockIdx.x*64;
  const int tid = threadIdx.x;
  const int tx = tid & 15, ty = tid >> 4;

  float acc[4][4];
  #pragma unroll
  for (int i=0;i<4;i++)
    #pragma unroll
    for (int j=0;j<4;j++) acc[i][j] = 0.f;

  for (int kt = 0; kt < 256; kt += 16) {
    int ka = tid & 15, ma = tid >> 4;
    #pragma unroll
    for (int q=0;q<4;q++){
      int m = ma + q*16;
      As[ka][m] = A[(size_t)(mb+m)*512 + kt+ka];
      Bs[ka][m] = B[(size_t)(nb+m)*512 + kt+ka];
    }
    __syncthreads();
    #pragma unroll
    for (int k=0;k<16;k++){
      float a[4], bv[4];
      #pragma unroll
      for (int i=0;i<4;i++) a[i] = As[k][ty*4+i];
      #pragma unroll
      for (int j=0;j<4;j++) bv[j] = Bs[k][tx*4+j];
      #pragma unroll
      for (int i=0;i<4;i++)
        #pragma unroll
        for (int j=0;j<4;j++) acc[i][j] += a[i]*bv[j];
    }
    __syncthreads();
  }
  float c[4][4];
  #pragma unroll
  for (int i=0;i<4;i++){
    int m = mb + ty*4 + i;
    float um = Uv[m];
    #pragma unroll
    for (int j=0;j<4;j++){
      int n = nb + tx*4 + j;
      c[i][j] = acc[i][j] / dsmall(um * Vv[n]);
      C[(size_t)m*256 + n] = c[i][j];
    }
  }
  // row partials (sum+max over this tile's 64 cols)
  float rs[4], rm[4];
  #pragma unroll
  for (int i=0;i<4;i++){
    rs[i] = c[i][0]+c[i][1]+c[i][2]+c[i][3];
    rm[i] = fmaxf(fmaxf(c[i][0], c[i][1]), fmaxf(c[i][2], c[i][3]));
    rs[i] += __shfl_xor(rs[i], 1, 64); rm[i] = fmaxf(rm[i], __shfl_xor(rm[i], 1, 64));
    rs[i] += __shfl_xor(rs[i], 2, 64); rm[i] = fmaxf(rm[i], __shfl_xor(rm[i], 2, 64));
    rs[i] += __shfl_xor(rs[i], 4, 64); rm[i] = fmaxf(rm[i], __shfl_xor(rm[i], 4, 64));
    rs[i] += __shfl_xor(rs[i], 8, 64); rm[i] = fmaxf(rm[i], __shfl_xor(rm[i], 8, 64));
  }
  if ((tid & 15) == 0){
    #pragma unroll
    for (int i=0;i<4;i++){
      PRS[((size_t)z*4 + blockIdx.x)*256 + mb + ty*4 + i] = rs[i];
      PRM[((size_t)z*4 + blockIdx.x)*256 + mb + ty*4 + i] = rm[i];
    }
  }
  // col partials via LDS
  __syncthreads();
  float* csum = &As[0][0];
  float* cmax = &Bs[0][0];
  #pragma unroll
  for (int j=0;j<4;j++){
    csum[ty*64 + tx*4 + j] = c[0][j]+c[1][j]+c[2][j]+c[3][j];
    cmax[ty*64 + tx*4 + j] = fmaxf(fmaxf(c[0][j], c[1][j]), fmaxf(c[2][j], c[3][j]));
  }
  __syncthreads();
  if (tid < 64){
    float s = 0.f, m = -INFINITY;
    #pragma unroll
    for (int r=0;r<16;r++){ s += csum[r*64 + tid]; m = fmaxf(m, cmax[r*64 + tid]); }
    PCS[((size_t)z*4 + blockIdx.y)*256 + nb + tid] = s;
    PCM[((size_t)z*4 + blockIdx.y)*256 + nb + tid] = m;
  }
}

__global__ void k_attcomb(const float* __restrict__ PRS, const float* __restrict__ PRM,
                          const float* __restrict__ PCS, const float* __restrict__ PCM,
                          float* __restrict__ RS_, float* __restrict__ RMAX_,
                          float* __restrict__ CS_, float* __restrict__ CMAX_){
  int z = blockIdx.x, j = threadIdx.x;
  float rs=0.f, rm=-INFINITY, cs=0.f, cm=-INFINITY;
  #pragma unroll
  for (int p=0;p<4;p++){
    size_t o = ((size_t)z*4 + p)*256 + j;
    rs += PRS[o]; rm = fmaxf(rm, PRM[o]);
    cs += PCS[o]; cm = fmaxf(cm, PCM[o]);
  }
  RS_[z*256 + j] = rs;  RMAX_[z*256 + j] = rm;
  CS_[z*256 + j] = cs;  CMAX_[z*256 + j] = cm;
}

// ---------------------------------------------------------------------------
// Fused attentive stats
// ---------------------------------------------------------------------------
__global__ __launch_bounds__(256) void k_attstat(
    const float* __restrict__ ATT_, const float* __restrict__ HS_,
    const float* __restrict__ RS_, const float* __restrict__ CS_,
    float* __restrict__ MEANH_, float* __restrict__ XH_,
    float* __restrict__ MEANP_, float* __restrict__ XP_)
{
  const int z16 = blockIdx.z;
  const int var = z16 >> 3;
  const int z = z16 & 7;
  const int d = z >> 2, b = z & 3;
  const float* A = ATT_ + (size_t)z*65536;
  const float* B = (var ? HS_ : HS_ + 524288) + d*256 + (size_t)b*131072;
  const float* U = (var ? CS_ : RS_) + z*256;
  float* C1 = (var ? MEANP_ : MEANH_) + (size_t)z*65536;
  float* C2 = (var ? XP_    : XH_   ) + (size_t)z*65536;

  __shared__ float As[16][68];
  __shared__ float Bs[16][68];
  const int mb = blockIdx.y*64, nb = blockIdx.x*64;
  const int tid = threadIdx.x;
  const int tx = tid & 15, ty = tid >> 4;

  float asum[4][4], amax[4][4];
  #pragma unroll
  for (int i=0;i<4;i++)
    #pragma unroll
    for (int j=0;j<4;j++){ asum[i][j]=0.f; amax[i][j]=-INFINITY; }

  for (int kt = 0; kt < 256; kt += 16) {
    if (var == 0) {
      int ka = tid & 15, ma = tid >> 4;
      #pragma unroll
      for (int q=0;q<4;q++)
        As[ka][ma+q*16] = A[(size_t)(mb+ma+q*16)*256 + kt+ka];
    } else {
      int ma = tid & 63, ka = tid >> 6;
      #pragma unroll
      for (int q=0;q<4;q++)
        As[ka+q*4][ma] = A[(size_t)(kt+ka+q*4)*256 + mb+ma];
    }
    {
      int nbi = tid & 63, kb = tid >> 6;
      #pragma unroll
      for (int q=0;q<4;q++)
        Bs[kb+q*4][nbi] = B[(size_t)(kt+kb+q*4)*512 + nb+nbi];
    }
    __syncthreads();
    #pragma unroll
    for (int k=0;k<16;k++){
      float a[4], bv[4];
      #pragma unroll
      for (int i=0;i<4;i++) a[i] = As[k][ty*4+i];
      #pragma unroll
      for (int j=0;j<4;j++) bv[j] = Bs[k][tx*4+j];
      #pragma unroll
      for (int i=0;i<4;i++)
        #pragma unroll
        for (int j=0;j<4;j++){
          float p = a[i]*bv[j];
          asum[i][j] += p;
          amax[i][j] = fmaxf(amax[i][j], p);
        }
    }
    __syncthreads();
  }
  #pragma unroll
  for (int i=0;i<4;i++){
    int m = mb + ty*4 + i;
    float ud = dsmall(U[m]);
    #pragma unroll
    for (int j=0;j<4;j++){
      int n = nb + tx*4 + j;
      C1[(size_t)m*256 + n] = asum[i][j] / ud;
      C2[(size_t)m*256 + n] = amax[i][j];
    }
  }
}

// ---------------------------------------------------------------------------
// Pairwise mp-match, fw+bw in one launch: z in 0..79 (dir = z>=40)
// ---------------------------------------------------------------------------
__global__ __launch_bounds__(256) void k_pmm2(
    const float* __restrict__ HS_,
    const float* __restrict__ w3, const float* __restrict__ w4,
    const float* __restrict__ WN1_, const float* __restrict__ WN2_,
    float* __restrict__ PARTR, float* __restrict__ PARTC)
{
  const int z = blockIdx.z;
  const int dir = z >= 40;
  const int zz = z - dir*40;
  const int bq = zz / 10, l = zz % 10;
  const float* A = HS_ + dir*256 + (size_t)bq*131072;
  const float* B = HS_ + 524288 + dir*256 + (size_t)bq*131072;
  const float* Wv = (dir ? w4 : w3) + l*256;
  const float* U = WN1_ + dir*10240 + bq*2560 + l*256;
  const float* V = WN2_ + dir*10240 + bq*2560 + l*256;

  __shared__ float As[16][68];
  __shared__ float Bs[16][68];
  const int mb = blockIdx.y*64, nb = blockIdx.x*64;
  const int tid = threadIdx.x;
  const int tx = tid & 15, ty = tid >> 4;

  float acc[4][4];
  #pragma unroll
  for (int i=0;i<4;i++)
    #pragma unroll
    for (int j=0;j<4;j++) acc[i][j] = 0.f;

  for (int kt = 0; kt < 256; kt += 16) {
    int ka = tid & 15, ma = tid >> 4;
    float w = Wv[kt+ka]; float w2 = w*w;
    #pragma unroll
    for (int q=0;q<4;q++){
      As[ka][ma+q*16] = A[(size_t)(mb+ma+q*16)*512 + kt+ka] * w2;
      Bs[ka][ma+q*16] = B[(size_t)(nb+ma+q*16)*512 + kt+ka];
    }
    __syncthreads();
    #pragma unroll
    for (int k=0;k<16;k++){
      float a[4], bv[4];
      #pragma unroll
      for (int i=0;i<4;i++) a[i] = As[k][ty*4+i];
      #pragma unroll
      for (int j=0;j<4;j++) bv[j] = Bs[k][tx*4+j];
      #pragma unroll
      for (int i=0;i<4;i++)
        #pragma unroll
        for (int j=0;j<4;j++) acc[i][j] += a[i]*bv[j];
    }
    __syncthreads();
  }
  float um[4], vn[4];
  #pragma unroll
  for (int i=0;i<4;i++) um[i] = U[mb + ty*4 + i];
  #pragma unroll
  for (int j=0;j<4;j++) vn[j] = V[nb + tx*4 + j];
  float c[4][4];
  #pragma unroll
  for (int i=0;i<4;i++)
    #pragma unroll
    for (int j=0;j<4;j++) c[i][j] = acc[i][j] / dsmall(um[i]*vn[j]);

  float rm[4];
  #pragma unroll
  for (int i=0;i<4;i++){
    rm[i] = fmaxf(fmaxf(c[i][0], c[i][1]), fmaxf(c[i][2], c[i][3]));
    rm[i] = fmaxf(rm[i], __shfl_xor(rm[i], 1, 64));
    rm[i] = fmaxf(rm[i], __shfl_xor(rm[i], 2, 64));
    rm[i] = fmaxf(rm[i], __shfl_xor(rm[i], 4, 64));
    rm[i] = fmaxf(rm[i], __shfl_xor(rm[i], 8, 64));
  }
  if ((tid & 15) == 0){
    #pragma unroll
    for (int i=0;i<4;i++)
      PARTR[((size_t)z*4 + blockIdx.x)*256 + mb + ty*4 + i] = rm[i];
  }
  __syncthreads();
  float* colp = &As[0][0];
  #pragma unroll
  for (int j=0;j<4;j++)
    colp[ty*64 + tx*4 + j] = fmaxf(fmaxf(c[0][j], c[1][j]), fmaxf(c[2][j], c[3][j]));
  __syncthreads();
  if (tid < 64){
    float m = colp[tid];
    #pragma unroll
    for (int r=1;r<16;r++) m = fmaxf(m, colp[r*64 + tid]);
    PARTC[((size_t)z*4 + blockIdx.y)*256 + nb + tid] = m;
  }
}

__global__ void k_pcomb(const float* __restrict__ PARTR, const float* __restrict__ PARTC,
                        float* __restrict__ MMRo, float* __restrict__ MMCo){
  int z = blockIdx.x, i = threadIdx.x;
  size_t b0 = (size_t)z*4*256 + i;
  float r = fmaxf(fmaxf(PARTR[b0], PARTR[b0+256]), fmaxf(PARTR[b0+512], PARTR[b0+768]));
  float c = fmaxf(fmaxf(PARTC[b0], PARTC[b0+256]), fmaxf(PARTC[b0+512], PARTC[b0+768]));
  MMRo[(size_t)z*256 + i] = r;
  MMCo[(size_t)z*256 + i] = c;
}

// ---------------------------------------------------------------------------
// LSTM scan (R14-proven config, verbatim): 16 teams (8/dir) x 8 WGs, 1 seq
// per team. bx<128: scan, team = bx&15, wg = bx>>4, d = team>>3, sq = team&7.
// Flag posted by tid==0 AFTER B2 (barrier drain does the vmcnt work for
// free -- R15's early-flag variant measured worse). bx>=128: aux work.
// ---------------------------------------------------------------------------
__global__ __launch_bounds__(256, 1) void k_scanaux(
    const float* __restrict__ PREf, const float* __restrict__ PREb,
    const float* __restrict__ WTf, const float* __restrict__ WTb,
    float* __restrict__ Hbuf, int* __restrict__ flg,
    float* __restrict__ HSo, float* __restrict__ HTo,
    int do_aux,
    const float* __restrict__ fc1W, float* __restrict__ W1T,
    const float* __restrict__ aWhhF, float* __restrict__ WTaggF,
    const float* __restrict__ aWhhB, float* __restrict__ WTaggB,
    const float* __restrict__ left, const float* __restrict__ right,
    float* __restrict__ XM)
{
  __shared__ float Wl[256][128];     // 128 KB (aux reuses as 32x33 tile)
  __shared__ float hl[256];          // 1 KB
  __shared__ float red[4][4][40];    // 2.5 KB red[kp][cc][gq]

  const int bx = blockIdx.x;
  const int tid = threadIdx.x;

  if (bx >= 128) {
    if (!do_aux) return;
    float (*tl)[33] = (float(*)[33])Wl;
    const int aux = bx - 128;         // 0..63
    for (int u = aux; u < 816 + 512 + 8; u += 64) {
      if (u < 816) {                // fc1W (512x1626) -> W1T (1626x512)
        int tI = u % 16, tJ = u / 16;
        int r0 = tI*32, c0 = tJ*32;
        for (int e = tid; e < 1024; e += 256) {
          int rr = e >> 5, cc = e & 31;
          int c = c0 + cc;
          tl[rr][cc] = (c < 1626) ? fc1W[(size_t)(r0+rr)*1626 + c] : 0.f;
        }
        __syncthreads();
        for (int e = tid; e < 1024; e += 256) {
          int cc = e >> 5, rr = e & 31;
          int c = c0 + cc;
          if (c < 1626) W1T[(size_t)c*512 + r0 + rr] = tl[rr][cc];
        }
        __syncthreads();
      } else if (u < 1328) {        // aWhh (1024x256) -> WTagg (256x1024)
        int u2 = u - 816;
        const float* S = (u2 >= 256) ? aWhhB : aWhhF;
        float* D = (u2 >= 256) ? WTaggB : WTaggF;
        int tile = u2 & 255;
        int r0 = (tile >> 3)*32, c0 = (tile & 7)*32;
        for (int e = tid; e < 1024; e += 256) {
          int rr = e >> 5, cc = e & 31;
          tl[rr][cc] = S[(size_t)(r0+rr)*256 + c0 + cc];
        }
        __syncthreads();
        for (int e = tid; e < 1024; e += 256) {
          int cc = e >> 5, rr = e & 31;
          D[(size_t)(c0+cc)*1024 + r0 + rr] = tl[rr][cc];
        }
        __syncthreads();
      } else {                      // means
        int m = u - 1328;
        int b = m & 3, sideR = m >> 2;
        const float* src = sideR ? right : left;
        for (int ch = tid; ch < 300; ch += 256) {
          float s = 0.f;
          for (int t = 0; t < 256; t++) s += src[((size_t)(b*256+t))*300 + ch];
          XM[b*600 + sideR*300 + ch] = s * (1.f/256.f);
        }
      }
    }
    return;
  }

  // ----------------- scan path -----------------
  const int team = bx & 15;
  const int d  = team >> 3;
  const int sq = team & 7;
  const int wg = bx >> 4;
  const float* PRE = d ? PREb : PREf;
  const float* WT  = d ? WTb  : WTf;
  float* Hb = Hbuf + (size_t)team*512;
  int* fl = flg + team*256;

  const int kc = tid >> 5;   // k-chunk 0..7
  const int gq = tid & 31;
  const int aj = tid & 31;   // activation col (tid<32)

  for (int e = tid; e < 256*128; e += 256) {
    int k = e >> 7, c = e & 127;
    Wl[k][c] = WT[(size_t)k*1024 + (c>>5)*256 + wg*32 + (c&31)];
  }
  hl[tid] = 0.f;
  float cst = 0.f;
  __syncthreads();

  for (int tt = 0; tt < 256; ++tt) {
    const int t = d ? 255 - tt : tt;
    const int wp = tt & 1;
    const int sp = (tt + 1) & 1;

    // prefetch PRE (tid<32)
    float pre0=0.f, pre1=0.f, pre2=0.f, pre3=0.f;
    if (tid < 32) {
      const size_t pbase = ((size_t)(sq*256 + t))*1024 + wg*32 + aj;
      pre0 = PRE[pbase];       pre1 = PRE[pbase + 256];
      pre2 = PRE[pbase + 512]; pre3 = PRE[pbase + 768];
    }

    // per-half-wave fetch of remote chunk kc (32 floats = 128B)
    if (tt > 0 && kc != wg) {
      const int* flp = &fl[kc*32];
      while (__hip_atomic_load(flp, __ATOMIC_RELAXED, __HIP_MEMORY_SCOPE_AGENT) < tt)
        __builtin_amdgcn_s_sleep(1);
      float v = __hip_atomic_load(&Hb[sp*256 + kc*32 + gq],
                                  __ATOMIC_RELAXED, __HIP_MEMORY_SCOPE_AGENT);
      hl[kc*32 + gq] = v;
    }

    // gate matmul: acc[cc] over 32 k of chunk kc
    float acc[4] = {0.f, 0.f, 0.f, 0.f};
    #pragma unroll 8
    for (int kk = 0; kk < 32; ++kk) {
      const int k = kc*32 + kk;
      float4 w = *(const float4*)&Wl[k][gq*4];
      float h = hl[k];
      acc[0] += h*w.x; acc[1] += h*w.y; acc[2] += h*w.z; acc[3] += h*w.w;
    }
    #pragma unroll
    for (int c2=0;c2<4;c2++)
      acc[c2] += __shfl_xor(acc[c2], 32, 64);
    if ((tid & 32) == 0) {
      const int kp = kc >> 1;
      #pragma unroll
      for (int c2=0;c2<4;c2++)
        red[kp][c2][gq] = acc[c2];
    }
    __syncthreads();   // B1

    float hreg = 0.f;
    if (tid < 32) {
      float g[4];
      #pragma unroll
      for (int gt=0; gt<4; ++gt) {
        const int c = gt*32 + aj;
        const int gqq = c >> 2, cc = c & 3;
        g[gt] = red[0][cc][gqq] + red[1][cc][gqq] + red[2][cc][gqq] + red[3][cc][gqq];
      }
      g[0] += pre0; g[1] += pre1; g[2] += pre2; g[3] += pre3;
      const float ig = sigf(g[0]), fg = sigf(g[1]), gg = tanhf(g[2]), og = sigf(g[3]);
      cst = fg*cst + ig*gg;
      hreg = og*tanhf(cst);
      hl[wg*32 + aj] = hreg;
      __hip_atomic_store(&Hb[wp*256 + wg*32 + aj], hreg,
                         __ATOMIC_RELAXED, __HIP_MEMORY_SCOPE_AGENT);
    }
    __syncthreads();   // B2: drains Hb stores + hl ds_writes

    if (tid == 0)
      __hip_atomic_store(&fl[wg*32], tt+1, __ATOMIC_RELAXED, __HIP_MEMORY_SCOPE_AGENT);

    if (tid < 32) {
      if (HSo) HSo[((size_t)(sq*256 + t))*512 + d*256 + wg*32 + aj] = hreg;
      if (HTo && tt == 255) HTo[((size_t)(sq*2 + d))*256 + wg*32 + aj] = hreg;
    }
  }
}

// ---------------------------------------------------------------------------
// Norms: bx<1024 -> row L2 norms of HS; else weighted norms
// ---------------------------------------------------------------------------
__global__ __launch_bounds__(256) void k_norms(const float* __restrict__ HS_,
                                               const float* __restrict__ w3, const float* __restrict__ w4,
                                               float* __restrict__ NORM_,
                                               float* __restrict__ WN1_, float* __restrict__ WN2_){
  const int bx = blockIdx.x;
  int lane = threadIdx.x & 63;
  if (bx < 1024) {
    int r = bx*4 + (threadIdx.x >> 6);
    int seq = r >> 9, d = (r >> 8) & 1, i = r & 255;
    const float* row = HS_ + ((size_t)(seq*256 + i))*512 + d*256;
    float s = 0.f;
    #pragma unroll
    for (int q=0;q<4;q++){ float v = row[lane + 64*q]; s += v*v; }
    for (int off=32; off; off>>=1) s += __shfl_xor(s, off, 64);
    if (lane == 0) NORM_[r] = sqrtf(s);
  } else {
    int rid = (bx-1024)*4 + (threadIdx.x >> 6);
    int side = rid / 20480; int rem = rid % 20480;
    int d = rem / 10240; int rem2 = rem % 10240;
    int b = rem2 / 2560; int l = (rem2 / 256) % 10; int i = rem2 & 255;
    int seq = side ? 4+b : b;
    const float* row = HS_ + ((size_t)(seq*256 + i))*512 + d*256;
    const float* w = (d ? w4 : w3) + l*256;
    float s = 0.f;
    #pragma unroll
    for (int q=0;q<4;q++){ float wv = w[lane+64*q]; float v = row[lane+64*q]; s += wv*wv*v*v; }
    for (int off=32; off; off>>=1) s += __shfl_xor(s, off, 64);
    if (lane == 0) (side ? WN2_ : WN1_)[rem] = sqrtf(s);
  }
}

// ---------------------------------------------------------------------------
// Assemble mv rows (62 channels)
// ---------------------------------------------------------------------------
__global__ __launch_bounds__(256) void k_mv(
    const float* __restrict__ HS_, const float* __restrict__ MEANH_, const float* __restrict__ MEANP_,
    const float* __restrict__ XH_, const float* __restrict__ XP_,
    const float* __restrict__ RS_, const float* __restrict__ RMAX_,
    const float* __restrict__ CS_, const float* __restrict__ CMAX_,
    const float* __restrict__ MMR_, const float* __restrict__ MMC_,
    const float* __restrict__ w5, const float* __restrict__ w6,
    const float* __restrict__ w7, const float* __restrict__ w8,
    float* __restrict__ MV_)
{
  const int blk = blockIdx.x;
  const int side = blk >> 10, b = (blk >> 8) & 3, i = blk & 255;
  const int wv = threadIdx.x >> 6, lane = threadIdx.x & 63;
  float* mvrow = MV_ + (size_t)blk*62;

  if (threadIdx.x == 0){
    const float* rmax = side ? CMAX_ : RMAX_;
    const float* rsum = side ? CS_   : RS_;
    mvrow[0] = rmax[b*256 + i];
    mvrow[1] = rsum[b*256 + i] * (1.f/256.f);
  }
  if (threadIdx.x < 20){
    int dd = threadIdx.x / 10, l = threadIdx.x % 10;
    const float* mm = side ? MMC_ : MMR_;
    mvrow[2 + dd*10 + l] = mm[dd*10240 + (b*10 + l)*256 + i];
  }
  const int d = wv & 1;
  const int seq = side ? 4+b : b;
  const float* arow = HS_ + ((size_t)(seq*256 + i))*512 + d*256;
  const float* Mside = side ? MEANP_ : MEANH_;
  const float* Xside = side ? XP_ : XH_;
  const float* brow = (wv < 2 ? Mside : Xside) + (size_t)d*262144 + (size_t)b*65536 + (size_t)i*256;
  const float* wp = (wv==0) ? w5 : (wv==1) ? w6 : (wv==2) ? w7 : w8;

  float av[4], bv[4];
  #pragma unroll
  for (int q=0;q<4;q++){ av[q] = arow[lane+64*q]; bv[q] = brow[lane+64*q]; }
  for (int l=0;l<10;l++){
    const float* wrow = wp + l*256;
    float s1=0.f, s2=0.f, s3=0.f;
    #pragma unroll
    for (int q=0;q<4;q++){
      float w = wrow[lane+64*q]; float w2v = w*w;
      s1 += w2v*av[q]*bv[q]; s2 += w2v*av[q]*av[q]; s3 += w2v*bv[q]*bv[q];
    }
    for (int off=32; off; off>>=1){
      s1 += __shfl_xor(s1,off,64); s2 += __shfl_xor(s2,off,64); s3 += __shfl_xor(s3,off,64);
    }
    if (lane == 0) mvrow[22 + wv*10 + l] = s1 / fmaxf(sqrtf(s2)*sqrtf(s3), EPSV);
  }
}

// ---------------------------------------------------------------------------
// Fused head: fc1 (tanh) + fc2
// ---------------------------------------------------------------------------
__global__ __launch_bounds__(512) void k_fc12(const float* __restrict__ HT_,
                                              const float* __restrict__ XM,
                                              const float* __restrict__ W1T,
                                              const float* __restrict__ b1,
                                              const float* __restrict__ W2,
                                              const float* __restrict__ b2,
                                              float* __restrict__ out){
  __shared__ float x[1626];
  __shared__ float xs2[512];
  int b = blockIdx.x, t = threadIdx.x;
  if (t < 256){
    x[t]       = HT_[(b*2+0)*256 + t];
    x[256+t]   = HT_[(b*2+1)*256 + t];
    x[512+t]   = HT_[((4+b)*2+0)*256 + t];
    x[768+t]   = HT_[((4+b)*2+1)*256 + t];
  }
  if (t == 0){ x[1024] = 0.5f; x[1025] = 0.5f; }
  if (t < 300){ x[1026+t] = XM[b*600 + t]; x[1326+t] = XM[b*600 + 300 + t]; }
  __syncthreads();
  float acc = b1[t];
  for (int k=0;k<1626;k++) acc += x[k]*W1T[(size_t)k*512 + t];
  xs2[t] = tanhf(acc);
  __syncthreads();
  if (t < 22){
    float o = b2[t];
    const float* wr = W2 + (size_t)t*512;
    for (int k=0;k<512;k++) o += xs2[k]*wr[k];
    out[b*22 + t] = o;
  }
}

// ---------------------------------------------------------------------------
extern "C" void kernel_launch(void* const* d_in, const int* in_sizes, int n_in,
                              void* d_out, int out_size, void* d_ws, size_t ws_size,
                              hipStream_t stream) {
  const float* left  = (const float*)d_in[0];
  const float* right = (const float*)d_in[1];
  const float* cWihF = (const float*)d_in[2];
  const float* cWhhF = (const float*)d_in[3];
  const float* cbF   = (const float*)d_in[4];
  const float* cWihB = (const float*)d_in[5];
  const float* cWhhB = (const float*)d_in[6];
  const float* cbB   = (const float*)d_in[7];
  const float* aWihF = (const float*)d_in[8];
  const float* aWhhF = (const float*)d_in[9];
  const float* abF   = (const float*)d_in[10];
  const float* aWihB = (const float*)d_in[11];
  const float* aWhhB = (const float*)d_in[12];
  const float* abB   = (const float*)d_in[13];
  const float* w3 = (const float*)d_in[14];
  const float* w4 = (const float*)d_in[15];
  const float* w5 = (const float*)d_in[16];
  const float* w6 = (const float*)d_in[17];
  const float* w7 = (const float*)d_in[18];
  const float* w8 = (const float*)d_in[19];
  const float* fc1W = (const float*)d_in[20];
  const float* fc1b = (const float*)d_in[21];
  const float* fc2W = (const float*)d_in[22];
  const float* fc2b = (const float*)d_in[23];
  float* out = (float*)d_out;
  float* ws = (float*)d_ws;

  // workspace layout (floats)
  float* WT    = ws;                 // 4 * 262144
  float* PREf  = ws + 1048576;       // 2097152
  float* PREb  = ws + 3145728;       // 2097152
  float* HS    = ws + 5242880;       // 1048576
  float* NORM  = ws + 6291456;       // 4096
  float* ATT   = ws + 6295552;       // 524288
  float* RS    = ws + 6819840;       // 2048
  float* RMAX  = ws + 6821888;       // 2048
  float* CS    = ws + 6823936;       // 2048
  float* CMAX  = ws + 6825984;       // 2048
  float* MEANH = ws + 6828032;       // 524288
  float* MEANP = ws + 7352320;       // 524288
  float* XH    = ws + 7876608;       // 524288
  float* XP    = ws + 8400896;       // 524288
  float* WN1   = ws + 8925184;       // 20480
  float* WN2   = ws + 8945664;       // 20480
  float* MM    = ws + 8966144;       // 2621440 scratch
  float* MMR   = ws + 11587584;      // 20480
  float* MMC   = ws + 11608064;      // 20480
  float* MV    = ws + 11628544;      // 126976
  float* HT    = ws + 11755520;      // 4096
  float* XM    = ws + 11759616;      // 2400
  float* W1T   = ws + 11764064;      // 832512

  // MM overlays (time-multiplexed)
  float* HXB  = MM;                   // scans: 8192 floats (16 teams x 512)
  int*   FLG  = (int*)(MM + 8192);    // scans: 4096 ints
  float* PRS  = MM;                   // att partials: 4 x 8192
  float* PRM  = MM + 8192;
  float* PCS  = MM + 16384;
  float* PCM  = MM + 24576;
  float* PARTR= MM;                   // pairwise: 81920
  float* PARTC= MM + 81920;           // 81920

  // 1. ctx Whh transposes
  k_transpose2<<<dim3(8,32,2), dim3(32,32), 0, stream>>>(cWhhF, cWhhB, WT, WT + 262144);

  // 2. ctx projections
  k_proj<<<dim3(16,16,4),256,0,stream>>>(left, right, cWihF, cWihB, cbF, cbB, PREf, PREb);

  // 3. ctx scan (8 teams/dir, 1 seq/team) + hidden aux work
  hipMemsetAsync(FLG, 0, 4096*sizeof(int), stream);
  k_scanaux<<<192,256,0,stream>>>(PREf, PREb, WT, WT+262144, HXB, FLG, HS, nullptr,
                                  1, fc1W, W1T, aWhhF, WT+524288, aWhhB, WT+786432,
                                  left, right, XM);

  // 4. norms
  k_norms<<<11264,256,0,stream>>>(HS, w3, w4, NORM, WN1, WN2);

  // 5. att cosine matrix with fused reduction partials + combine
  k_att<<<dim3(4,4,8),256,0,stream>>>(HS, NORM, ATT, PRS, PRM, PCS, PCM);
  k_attcomb<<<8,256,0,stream>>>(PRS, PRM, PCS, PCM, RS, RMAX, CS, CMAX);

  // 6. attentive means and maxes
  k_attstat<<<dim3(4,4,16),256,0,stream>>>(ATT, HS, RS, CS, MEANH, XH, MEANP, XP);

  // 7. pairwise mp-match + combine
  k_pmm2<<<dim3(4,4,80),256,0,stream>>>(HS, w3, w4, WN1, WN2, PARTR, PARTC);
  k_pcomb<<<80,256,0,stream>>>(PARTR, PARTC, MMR, MMC);

  // 8. assemble mv
  k_mv<<<2048,256,0,stream>>>(HS, MEANH, MEANP, XH, XP, RS, RMAX, CS, CMAX,
                              MMR, MMC, w5, w6, w7, w8, MV);

  // 9. agg projections
  k_aggproj<<<dim3(16,32,2),256,0,stream>>>(MV, aWihF, aWihB, abF, abB, PREf, PREb);

  // 10. agg scan (no aux)
  hipMemsetAsync(FLG, 0, 4096*sizeof(int), stream);
  k_scanaux<<<192,256,0,stream>>>(PREf, PREb, WT+524288, WT+786432, HXB, FLG, nullptr, HT,
                                  0, fc1W, W1T, aWhhF, WT+524288, aWhhB, WT+786432,
                                  left, right, XM);

  // 11. fused head
  k_fc12<<<4,512,0,stream>>>(HT, XM, W1T, fc1b, fc2W, fc2b, out);
}